// Round 17
// baseline (189.522 us; speedup 1.0000x reference)
//
#include <hip/hip_runtime.h>

constexpr int BATCH = 8;
constexpr int PPC   = 2048;            // points per cloud
constexpr int NPT   = BATCH * PPC;     // 16384 points
constexpr int OCH   = 64;              // out channels (= in channels)
constexpr int KNN_K = 20;
constexpr int NEDGE = NPT * KNN_K;     // 327680 edges
constexpr int REVCAP = 128;            // per-row reverse-adjacency capacity
constexpr int OVCAP  = 8192;           // overflow list capacity
constexpr int QCAP   = 48;             // per-point qualifier capacity
constexpr int NPART  = 32;             // stat partial buffers (de-contended atomics)

typedef short short8 __attribute__((ext_vector_type(8)));
typedef float float4v __attribute__((ext_vector_type(4)));

// XCD-aware swizzle: blocks of one cloud all land on one XCD
__device__ __forceinline__ int xcd_swizzle(int b, int nper) {
  return (b & 7) * nper + (b >> 3);
}

__device__ __forceinline__ unsigned short bfr(float f) {  // f32 -> bf16 RNE
  unsigned u = __float_as_uint(f);
  return (unsigned short)((u + 0x7FFFu + ((u >> 16) & 1u)) >> 16);
}
__device__ __forceinline__ short8 pack8(float4 a, float4 b) {
  short8 r;
  r[0] = (short)bfr(a.x); r[1] = (short)bfr(a.y);
  r[2] = (short)bfr(a.z); r[3] = (short)bfr(a.w);
  r[4] = (short)bfr(b.x); r[5] = (short)bfr(b.y);
  r[6] = (short)bfr(b.z); r[7] = (short)bfr(b.w);
  return r;
}
__device__ __forceinline__ unsigned umed3(unsigned a, unsigned b, unsigned c) {
  unsigned d;
  asm("v_med3_u32 %0, %1, %2, %3" : "=v"(d) : "v"(a), "v"(b), "v"(c));
  return d;
}

// -------------------------------------------- kNN + fused BN1 stats --------
// P1: per-lane top-3 proxies WITHOUT self-mask (self d2=0 is the global
//     minimum; taking the 21st order statistic of the 48 heads still bounds
//     the true 20th-excluding-self).
// P2: push qualifiers (proxy <= T+16ulp, excl. self) with EXACT d2 keys.
// P3: exact (d2,index) rank -> nbr/rev emit.
// Fused epilogue: each lane (channel-quad s) gathers the point's 20 y-rows
// + z row and accumulates BN1 sum/sumsq -> 32-way partial buffers.
__global__ __launch_bounds__(256) void knn_kernel(const float* __restrict__ pos,
                                                  const float4* __restrict__ yv4,
                                                  const float4* __restrict__ zv4,
                                                  const float* __restrict__ b1,
                                                  int* __restrict__ nbr,
                                                  int* __restrict__ cnt,
                                                  int* __restrict__ ovf_cnt,
                                                  int* __restrict__ ovf,
                                                  int* __restrict__ rev,
                                                  float* __restrict__ bn1p) {
  __shared__ float4 cps[8 * 257];                 // region r at r*257 (+pad)
  __shared__ unsigned long long qk[16][QCAP];     // per-point qualifiers
  __shared__ int qn[16];
  __shared__ float ss[2][64];
  const int t  = threadIdx.x;
  const int pl = t >> 4;                     // point-local 0..15
  const int s  = t & 15;                     // split / channel-quad 0..15
  const int lane = t & 63;
  const int eb = xcd_swizzle(blockIdx.x, NPT / 16 / 8);
  const int i  = eb * 16 + pl;
  const int cbase = i & ~(PPC - 1);

  for (int u = t; u < PPC; u += 256) {
    int j = cbase + u;
    float ax = pos[3 * j], ay = pos[3 * j + 1], az = pos[3 * j + 2];
    cps[(u >> 8) * 257 + (u & 255)] = make_float4(ax, ay, az, ax * ax + ay * ay + az * az);
  }
  if (t < 16) qn[t] = 0;
  __syncthreads();

  const int il = i - cbase;
  const float4 me = cps[(il >> 8) * 257 + (il & 255)];
  const float px = me.x, py = me.y, pz = me.z, sqi = me.w;
  const int jbase = s * 128;
  const float4* __restrict__ cp = &cps[(s >> 1) * 257 + (s & 1) * 128];

  // ---- pass 1: per-lane top-3 proxies, self included (no mask) ----
  unsigned kd[3];
  kd[0] = kd[1] = kd[2] = 0xFFFFFFFFu;
  for (int u = 0; u < 128; ++u) {
    float4 c = cp[u];
    float pr = fmaf(-px, c.x, fmaf(-py, c.y, fmaf(-pz, c.z, fmaf(0.5f, c.w, 1000.f))));
    unsigned ck = __float_as_uint(pr);
    kd[2] = umed3(kd[1], kd[2], ck);
    kd[1] = umed3(kd[0], kd[1], ck);
    kd[0] = kd[0] < ck ? kd[0] : ck;
  }

  // ---- merge: 21st smallest of the 48 heads -> T (bounds 20th excl self) --
  unsigned T = 0xFFFFFFFFu;
  int cum = 0;
  const int grp = lane & 48;
#pragma unroll
  for (int r = 0; r < KNN_K + 1; ++r) {
    unsigned w = kd[0];
#pragma unroll
    for (int m = 1; m < 16; m <<= 1) {
      unsigned o = (unsigned)__shfl_xor((int)w, m, 16);
      w = o < w ? o : w;
    }
    bool pop = (kd[0] == w);
    unsigned long long bal = __ballot(pop);
    int mcount = __popc((int)((bal >> grp) & 0xFFFFull));
    if (cum < KNN_K + 1) T = w;
    cum += mcount;
    if (pop) { kd[0] = kd[1]; kd[1] = kd[2]; kd[2] = 0xFFFFFFFFu; }
  }
  const unsigned Tq = T + 16;   // +16 ulp safety margin

  // ---- pass 2: push qualifiers (excl self) with EXACT d2 key ----
  for (int u = 0; u < 128; ++u) {
    float4 c = cp[u];
    float pr = fmaf(-px, c.x, fmaf(-py, c.y, fmaf(-pz, c.z, fmaf(0.5f, c.w, 1000.f))));
    unsigned ck = __float_as_uint(pr);
    if (ck <= Tq && jbase + u != il) {
      float d2 = sqi + c.w - 2.0f * (px * c.x + py * c.y + pz * c.z);
      d2 = d2 > 0.f ? d2 : 0.f;
      int slot = atomicAdd(&qn[pl], 1);
      if (slot < QCAP)
        qk[pl][slot] = ((unsigned long long)__float_as_uint(d2) << 32) | (unsigned)(jbase + u);
    }
  }
  __syncthreads();

  // ---- pass 3: exact rank + emit nbr/rev; collect res in all lanes ----
  int n = qn[pl]; n = n < QCAP ? n : QCAP;
  int res[KNN_K];
  for (int base = 0; base < n; base += 16) {
    int e = base + s;
    int rnk = -1, jloc = 0;
    if (e < n) {
      unsigned long long mk = qk[pl][e];
      int rank = 0;
      for (int o = 0; o < n; ++o) rank += (qk[pl][o] < mk) ? 1 : 0;
      jloc = (int)(mk & 0xFFFFFFFFull);
      if (rank < KNN_K) {
        rnk = rank;
        int j = cbase + jloc;
        int eid = i * KNN_K + rank;
        nbr[eid] = j;
        int slot = atomicAdd(&cnt[j], 1);
        if (slot < REVCAP) rev[j * REVCAP + slot] = i;   // center index
        else { int ov = atomicAdd(ovf_cnt, 1); if (ov < OVCAP) ovf[ov] = eid; }
      }
    }
    // broadcast winners of this batch into res[] on all 16 lanes of the point
    unsigned long long bal = __ballot(rnk >= 0);
    unsigned short msk = (unsigned short)((bal >> grp) & 0xFFFFull);
    while (msk) {
      int src = __ffs((int)msk) - 1;
      int r  = __shfl(rnk,  grp + src);
      int jl = __shfl(jloc, grp + src);
      res[r] = jl;
      msk &= msk - 1;
    }
  }

  // ---- fused BN1 stats: lane s owns channels s*4..s*4+3 ----
  const float4 bo = reinterpret_cast<const float4*>(b1)[s];
  float4 z = zv4[(size_t)i * 16 + s];
  float4 zb = make_float4(z.x + bo.x, z.y + bo.y, z.z + bo.z, z.w + bo.w);
  float4 s1 = make_float4(0, 0, 0, 0), s2 = make_float4(0, 0, 0, 0);
#pragma unroll
  for (int q = 0; q < KNN_K; ++q) {
    float4 y = yv4[(size_t)(cbase + res[q]) * 16 + s];
    float sx = y.x + zb.x, sy = y.y + zb.y, sz = y.z + zb.z, sw = y.w + zb.w;
    s1.x += sx; s1.y += sy; s1.z += sz; s1.w += sw;
    s2.x += sx * sx; s2.y += sy * sy; s2.z += sz * sz; s2.w += sw * sw;
  }
  s1.x += __shfl_xor(s1.x, 16); s1.y += __shfl_xor(s1.y, 16);
  s1.z += __shfl_xor(s1.z, 16); s1.w += __shfl_xor(s1.w, 16);
  s2.x += __shfl_xor(s2.x, 16); s2.y += __shfl_xor(s2.y, 16);
  s2.z += __shfl_xor(s2.z, 16); s2.w += __shfl_xor(s2.w, 16);
  s1.x += __shfl_xor(s1.x, 32); s1.y += __shfl_xor(s1.y, 32);
  s1.z += __shfl_xor(s1.z, 32); s1.w += __shfl_xor(s1.w, 32);
  s2.x += __shfl_xor(s2.x, 32); s2.y += __shfl_xor(s2.y, 32);
  s2.z += __shfl_xor(s2.z, 32); s2.w += __shfl_xor(s2.w, 32);
  if (t < 128) ss[t >> 6][t & 63] = 0.f;
  __syncthreads();
  if ((t & 48) == 0) {
    atomicAdd(&ss[0][s * 4 + 0], s1.x); atomicAdd(&ss[0][s * 4 + 1], s1.y);
    atomicAdd(&ss[0][s * 4 + 2], s1.z); atomicAdd(&ss[0][s * 4 + 3], s1.w);
    atomicAdd(&ss[1][s * 4 + 0], s2.x); atomicAdd(&ss[1][s * 4 + 1], s2.y);
    atomicAdd(&ss[1][s * 4 + 2], s2.z); atomicAdd(&ss[1][s * 4 + 3], s2.w);
  }
  __syncthreads();
  const int pb = (blockIdx.x & (NPART - 1)) * 128;
  if (t < 64)       atomicAdd(&bn1p[pb + t], ss[0][t]);
  else if (t < 128) atomicAdd(&bn1p[pb + 64 + (t - 64)], ss[1][t - 64]);
}

// ------------------------- node-level layer-1 GEMM (16 nodes/block) --------
__global__ __launch_bounds__(256) void node_gemm(const float* __restrict__ x,
                                                 const float* __restrict__ W1,
                                                 float* __restrict__ yv,
                                                 float* __restrict__ zv) {
  __shared__ float wa[64][65];
  __shared__ float wb[64][65];
  __shared__ float xs[16][64];
  const int t = threadIdx.x;
  for (int m = t; m < 8192; m += 256) {
    int o = m >> 7, c2 = m & 127;
    float w = W1[m];
    if (c2 < 64) wa[c2][o] = w; else wb[c2 - 64][o] = w;
  }
  for (int m = t; m < 1024; m += 256)
    xs[m >> 6][m & 63] = x[(size_t)blockIdx.x * 1024 + m];
  __syncthreads();
  const int g = t >> 6, o = t & 63;
  float accA[4] = {0, 0, 0, 0}, accB[4] = {0, 0, 0, 0};
#pragma unroll 4
  for (int c = 0; c < 64; ++c) {
    float w_a = wa[c][o], w_b = wb[c][o];
#pragma unroll
    for (int q = 0; q < 4; ++q) {
      float xv = xs[g * 4 + q][c];
      accA[q] = fmaf(xv, w_a, accA[q]);
      accB[q] = fmaf(xv, w_b, accB[q]);
    }
  }
#pragma unroll
  for (int q = 0; q < 4; ++q) {
    size_t n = (size_t)blockIdx.x * 16 + g * 4 + q;
    yv[n * 64 + o] = accA[q] - accB[q];
    zv[n * 64 + o] = accB[q];
  }
}

// ------------- pre-apply BN1 (sums 32 partials block-locally) --------------
__global__ __launch_bounds__(256) void scale_yz(
    const float4* __restrict__ yv4, const float4* __restrict__ zv4,
    const float* __restrict__ bn1p, const float* __restrict__ g1,
    const float* __restrict__ beta1, const float* __restrict__ b1,
    float4* __restrict__ ys4, float4* __restrict__ zs4) {
  __shared__ float red[128];
  const int t = threadIdx.x;
  if (t < 128) {
    float v = 0.f;
#pragma unroll
    for (int k = 0; k < NPART; ++k) v += bn1p[k * 128 + t];
    red[t] = v;
  }
  __syncthreads();
  const int idx = blockIdx.x * 256 + t;   // over NPT*16
  const int c4 = idx & 15;
  constexpr float invE = 1.0f / NEDGE;
  float a[4], c[4];
#pragma unroll
  for (int q = 0; q < 4; ++q) {
    int ch = c4 * 4 + q;
    float mu  = red[ch] * invE;
    float var = red[64 + ch] * invE - mu * mu;
    float av  = g1[ch] * rsqrtf(var + 1e-5f);
    a[q] = av;
    c[q] = fmaf(b1[ch], av, beta1[ch] - mu * av);
  }
  float4 y = yv4[idx];
  float4 z = zv4[idx];
  ys4[idx] = make_float4(y.x * a[0], y.y * a[1], y.z * a[2], y.w * a[3]);
  zs4[idx] = make_float4(fmaf(z.x, a[0], c[0]), fmaf(z.y, a[1], c[1]),
                         fmaf(z.z, a[2], c[2]), fmaf(z.w, a[3], c[3]));
}

// ----------- per-wave row-owned GEMM2 (bf16 MFMA), row-pipelined -----------
__global__ __launch_bounds__(256) void gemm2_row(
    const float4* __restrict__ ys4, const float4* __restrict__ zs4,
    const float* __restrict__ W2, const float* __restrict__ b2,
    const int* __restrict__ cnt, const int* __restrict__ rev,
    float* __restrict__ bn2p, float* __restrict__ mmax,
    float* __restrict__ mmin) {
  __shared__ float ss[2][64];
  const int t = threadIdx.x, lane = t & 63;
  const int col = lane & 15, quad = lane >> 4;
  const int eb = xcd_swizzle(blockIdx.x, NPT / 16 / 8);
  const int wid = eb * 4 + (t >> 6);

  short8 bf0[4], bf1[4];
  const float4* __restrict__ W2v = (const float4*)W2;
#pragma unroll
  for (int nt = 0; nt < 4; ++nt) {
    int row = nt * 16 + col;
    float4 wa = W2v[row * 16 + quad * 2];
    float4 wb = W2v[row * 16 + quad * 2 + 1];
    float4 wc = W2v[row * 16 + 8 + quad * 2];
    float4 wd = W2v[row * 16 + 8 + quad * 2 + 1];
    bf0[nt] = pack8(wa, wb);
    bf1[nt] = pack8(wc, wd);
  }
  float b2r[4];
#pragma unroll
  for (int nt = 0; nt < 4; ++nt) b2r[nt] = b2[nt * 16 + col];

  int4 cq = *reinterpret_cast<const int4*>(&cnt[wid * 4]);
  int nA[4] = {cq.x, cq.y, cq.z, cq.w};
#pragma unroll
  for (int q = 0; q < 4; ++q) nA[q] = nA[q] < REVCAP ? nA[q] : REVCAP;

  float s1[4] = {0, 0, 0, 0}, s2[4] = {0, 0, 0, 0};
  int rv0 = rev[(size_t)(wid * 4) * REVCAP + lane];
  int rv1 = (nA[0] > 64) ? rev[(size_t)(wid * 4) * REVCAP + 64 + lane] : 0;
  float4 ya = ys4[(size_t)(wid * 4) * 16 + quad * 2];
  float4 yb = ys4[(size_t)(wid * 4) * 16 + quad * 2 + 1];
  float4 yc = ys4[(size_t)(wid * 4) * 16 + 8 + quad * 2];
  float4 yd = ys4[(size_t)(wid * 4) * 16 + 8 + quad * 2 + 1];

#pragma unroll
  for (int rr = 0; rr < 4; ++rr) {
    const int row = wid * 4 + rr;
    const int n = nA[rr];
    int nrv0 = 0, nrv1 = 0;
    float4 nya, nyb, nyc, nyd;
    if (rr < 3) {
      const int nrow = row + 1;
      nrv0 = rev[(size_t)nrow * REVCAP + lane];
      nrv1 = (nA[rr + 1] > 64) ? rev[(size_t)nrow * REVCAP + 64 + lane] : 0;
      nya = ys4[(size_t)nrow * 16 + quad * 2];
      nyb = ys4[(size_t)nrow * 16 + quad * 2 + 1];
      nyc = ys4[(size_t)nrow * 16 + 8 + quad * 2];
      nyd = ys4[(size_t)nrow * 16 + 8 + quad * 2 + 1];
    }
    float mx[4], mn[4];
#pragma unroll
    for (int nt = 0; nt < 4; ++nt) { mx[nt] = -1e30f; mn[nt] = 1e30f; }

    auto tile_body = [&](int tbase, float4 za, float4 zb, float4 zc, float4 zd) {
      float h[16];
      h[0]  = ya.x + za.x; h[1]  = ya.y + za.y; h[2]  = ya.z + za.z; h[3]  = ya.w + za.w;
      h[4]  = yb.x + zb.x; h[5]  = yb.y + zb.y; h[6]  = yb.z + zb.z; h[7]  = yb.w + zb.w;
      h[8]  = yc.x + zc.x; h[9]  = yc.y + zc.y; h[10] = yc.z + zc.z; h[11] = yc.w + zc.w;
      h[12] = yd.x + zd.x; h[13] = yd.y + zd.y; h[14] = yd.z + zd.z; h[15] = yd.w + zd.w;
      short8 af0, af1;
#pragma unroll
      for (int q = 0; q < 8; ++q) {
        float u0 = h[q]     > 0.f ? h[q]     : 0.f;
        float u1 = h[8 + q] > 0.f ? h[8 + q] : 0.f;
        af0[q] = (short)bfr(u0);
        af1[q] = (short)bfr(u1);
      }
      float4v acc[4];
#pragma unroll
      for (int nt = 0; nt < 4; ++nt) {
        acc[nt] = (float4v){0.f, 0.f, 0.f, 0.f};
        acc[nt] = __builtin_amdgcn_mfma_f32_16x16x32_bf16(af0, bf0[nt], acc[nt], 0, 0, 0);
        acc[nt] = __builtin_amdgcn_mfma_f32_16x16x32_bf16(af1, bf1[nt], acc[nt], 0, 0, 0);
      }
#pragma unroll
      for (int r = 0; r < 4; ++r) {
        bool v = (tbase + quad * 4 + r) < n;
#pragma unroll
        for (int nt = 0; nt < 4; ++nt) {
          float val = acc[nt][r] + b2r[nt];
          if (v) {
            s1[nt] += val; s2[nt] += val * val;
            mx[nt] = val > mx[nt] ? val : mx[nt];
            mn[nt] = val < mn[nt] ? val : mn[nt];
          }
        }
      }
    };

    int icA = __shfl(rv0, col);       icA = (col < n) ? icA : 0;
    int icB = __shfl(rv0, 16 + col);  icB = (16 + col < n) ? icB : 0;
    float4 zAa = zs4[(size_t)icA * 16 + quad * 2];
    float4 zAb = zs4[(size_t)icA * 16 + quad * 2 + 1];
    float4 zAc = zs4[(size_t)icA * 16 + 8 + quad * 2];
    float4 zAd = zs4[(size_t)icA * 16 + 8 + quad * 2 + 1];
    float4 zBa = zs4[(size_t)icB * 16 + quad * 2];
    float4 zBb = zs4[(size_t)icB * 16 + quad * 2 + 1];
    float4 zBc = zs4[(size_t)icB * 16 + 8 + quad * 2];
    float4 zBd = zs4[(size_t)icB * 16 + 8 + quad * 2 + 1];
    tile_body(0, zAa, zAb, zAc, zAd);
    if (n > 16) tile_body(16, zBa, zBb, zBc, zBd);
    for (int ti = 2; ti * 16 < n; ++ti) {
      int gi = ti * 16 + col;
      int v0 = __shfl(rv0, gi & 63);
      int v1 = __shfl(rv1, gi & 63);
      int ic = (gi < 64) ? v0 : v1;
      ic = (gi < n) ? ic : 0;
      float4 za = zs4[(size_t)ic * 16 + quad * 2];
      float4 zb = zs4[(size_t)ic * 16 + quad * 2 + 1];
      float4 zc = zs4[(size_t)ic * 16 + 8 + quad * 2];
      float4 zd = zs4[(size_t)ic * 16 + 8 + quad * 2 + 1];
      tile_body(ti * 16, za, zb, zc, zd);
    }
#pragma unroll
    for (int nt = 0; nt < 4; ++nt) {
      mx[nt] = fmaxf(mx[nt], __shfl_xor(mx[nt], 16));
      mx[nt] = fmaxf(mx[nt], __shfl_xor(mx[nt], 32));
      mn[nt] = fminf(mn[nt], __shfl_xor(mn[nt], 16));
      mn[nt] = fminf(mn[nt], __shfl_xor(mn[nt], 32));
    }
    if (quad == 0) {
#pragma unroll
      for (int nt = 0; nt < 4; ++nt) {
        mmax[(size_t)row * 64 + nt * 16 + col] = mx[nt];
        mmin[(size_t)row * 64 + nt * 16 + col] = mn[nt];
      }
    }
    rv0 = nrv0; rv1 = nrv1;
    ya = nya; yb = nyb; yc = nyc; yd = nyd;
  }
  // block-level stats reduction -> partial buffer (32-way de-contended)
  if (t < 128) ss[t >> 6][t & 63] = 0.f;
  __syncthreads();
#pragma unroll
  for (int nt = 0; nt < 4; ++nt) {
    s1[nt] += __shfl_xor(s1[nt], 16);
    s1[nt] += __shfl_xor(s1[nt], 32);
    s2[nt] += __shfl_xor(s2[nt], 16);
    s2[nt] += __shfl_xor(s2[nt], 32);
  }
  if (quad == 0) {
#pragma unroll
    for (int nt = 0; nt < 4; ++nt) {
      atomicAdd(&ss[0][nt * 16 + col], s1[nt]);
      atomicAdd(&ss[1][nt * 16 + col], s2[nt]);
    }
  }
  __syncthreads();
  const int pb = (blockIdx.x & (NPART - 1)) * 128;
  if (t < 64)       atomicAdd(&bn2p[pb + t], ss[0][t]);
  else if (t < 128) atomicAdd(&bn2p[pb + 64 + (t - 64)], ss[1][t - 64]);
}

// ---------------- finalize: BN2 affine of per-row max/min + relu + empties -
__global__ __launch_bounds__(256) void finalize_out(
    const float* __restrict__ bn2p, const float* __restrict__ g2,
    const float* __restrict__ beta2, const int* __restrict__ cnt,
    const float* __restrict__ mmax, const float* __restrict__ mmin,
    const int* __restrict__ ovf_cnt, const int* __restrict__ ovf,
    const int* __restrict__ nbr, const float* __restrict__ ys,
    const float* __restrict__ zs, const float* __restrict__ W2,
    const float* __restrict__ b2, float* __restrict__ outp) {
  __shared__ float red[128];
  const int t = threadIdx.x;
  if (t < 128) {
    float v = 0.f;
#pragma unroll
    for (int k = 0; k < NPART; ++k) v += bn2p[k * 128 + t];
    red[t] = v;
  }
  __syncthreads();
  const int idx = blockIdx.x * 256 + t;
  const int row = idx >> 6, ch = idx & 63;
  constexpr float invE = 1.0f / NEDGE;
  float mu  = red[ch] * invE;
  float var = red[64 + ch] * invE - mu * mu;
  float a2  = g2[ch] * rsqrtf(var + 1e-5f);
  float c2  = beta2[ch] - mu * a2;
  float h = (a2 >= 0.f) ? mmax[idx] : mmin[idx];
  int ov = ovf_cnt[0]; ov = ov > OVCAP ? OVCAP : ov;
  for (int u = 0; u < ov; ++u) {
    int e = ovf[u];
    if (nbr[e] == row) {
      int ic = e / KNN_K;
      float accv = 0.f;
      for (int k = 0; k < 64; ++k) {
        float hh = ys[(size_t)row * 64 + k] + zs[(size_t)ic * 64 + k];
        hh = hh > 0.f ? hh : 0.f;
        accv = fmaf(hh, W2[ch * 64 + k], accv);
      }
      float v = accv + b2[ch];
      if (a2 >= 0.f) h = v > h ? v : h; else h = v < h ? v : h;
    }
  }
  float o = (cnt[row] > 0) ? fmaf(h, a2, c2) : 0.0f;
  outp[idx] = o > 0.f ? o : 0.f;
}

// --------------------------------------------------------------- launch ----
extern "C" void kernel_launch(void* const* d_in, const int* in_sizes, int n_in,
                              void* d_out, int out_size, void* d_ws, size_t ws_size,
                              hipStream_t stream) {
  (void)in_sizes; (void)n_in; (void)out_size; (void)ws_size;
  const float* x     = (const float*)d_in[0];
  const float* pos   = (const float*)d_in[1];
  const float* W1    = (const float*)d_in[3];
  const float* b1    = (const float*)d_in[4];
  const float* g1    = (const float*)d_in[5];
  const float* beta1 = (const float*)d_in[6];
  const float* W2    = (const float*)d_in[7];
  const float* b2    = (const float*)d_in[8];
  const float* g2    = (const float*)d_in[9];
  const float* beta2 = (const float*)d_in[10];
  float* outp = (float*)d_out;

  char* w = (char*)d_ws;
  int*   nbr     = (int*)w;                            // 1,310,720 B
  float* yv      = (float*)(w + 1310720);              // 4,194,304 B
  float* zv      = (float*)(w + 5505024);              // 4,194,304 B
  int*   cnt     = (int*)(w + 9700352);                // 65,536 B
  int*   ovf_cnt = (int*)(w + 9765888);                // 64 B
  int*   ovf     = (int*)(w + 9765952);                // 32,768 B
  int*   rev     = (int*)(w + 9798720);                // 8,388,608 B -> 18,187,328
  float* mmax    = (float*)(w + 18187328);             // 4,194,304 B
  float* mmin    = (float*)(w + 22381632);             // 4,194,304 B -> 26,575,936
  float* ys      = (float*)(w + 26575936);             // 4,194,304 B
  float* zs      = (float*)(w + 30770240);             // 4,194,304 B -> 34,964,544
  float* bn1p    = (float*)(w + 34964544);             // 16,384 B (32x128)
  float* bn2p    = (float*)(w + 34980928);             // 16,384 B -> 34,997,312

  hipMemsetAsync(cnt, 0, 65536 + 64, stream);
  hipMemsetAsync(bn1p, 0, 32768, stream);

  node_gemm<<<NPT / 16, 256, 0, stream>>>(x, W1, yv, zv);
  knn_kernel<<<NPT / 16, 256, 0, stream>>>(pos, (const float4*)yv, (const float4*)zv,
                                           b1, nbr, cnt, ovf_cnt, ovf, rev, bn1p);
  scale_yz<<<NPT * 16 / 256, 256, 0, stream>>>(
      (const float4*)yv, (const float4*)zv, bn1p, g1, beta1, b1,
      (float4*)ys, (float4*)zs);
  gemm2_row<<<NPT / 16, 256, 0, stream>>>(
      (const float4*)ys, (const float4*)zs, W2, b2,
      cnt, rev, bn2p, mmax, mmin);
  finalize_out<<<NPT * 64 / 256, 256, 0, stream>>>(
      bn2p, g2, beta2, cnt, mmax, mmin, ovf_cnt, ovf, nbr,
      ys, zs, W2, b2, outp);
}